// Round 3
// baseline (566.392 us; speedup 1.0000x reference)
//
#include <hip/hip_runtime.h>

#define DD 256
#define TOTROWS (524288 * 2)
#define NBLOCKS 512
#define RPI 32                               // rows per iteration per block
#define ITERS (TOTROWS / (NBLOCKS * RPI))    // 64
#define XROW 528                             // bf16 row stride (bytes) = 33*16
#define YROW 1040                            // fp32 row stride (bytes) = 65*16
#define XB0 0
#define XB1 (RPI * XROW)                     // 16896
#define YB (2 * RPI * XROW)                  // 33792
#define SUMS (YB + RPI * YROW)               // 67072
#define MURS (SUMS + RPI * 8 * 8)            // 69120
#define CGB (MURS + RPI * 8)                 // 69376  (c, gamma, beta: 3*256 fp32)
#define LDS_TOTAL (CGB + 3 * 256 * 4)        // 72448  -> 2 blocks/CU

typedef __attribute__((ext_vector_type(8))) short short8;
typedef __attribute__((ext_vector_type(4))) float f32x4;
typedef __attribute__((ext_vector_type(2))) float f32x2;
typedef __attribute__((ext_vector_type(4))) unsigned short u16x4;

__device__ inline unsigned short f2bf(float x) {
    unsigned u = __builtin_bit_cast(unsigned, x);
    u += 0x7fffu + ((u >> 16) & 1u);  // RNE
    return (unsigned short)(u >> 16);
}
__device__ inline float bf2f(unsigned short h) {
    unsigned u = ((unsigned)h) << 16;
    return __builtin_bit_cast(float, u);
}

// ---------------- W = Wo @ Wv (bf16), c = Wo @ bv + bo ----------------
__global__ void wprep_kernel(const float* __restrict__ in_w,
                             const float* __restrict__ in_b,
                             const float* __restrict__ out_w,
                             const float* __restrict__ out_b,
                             unsigned short* __restrict__ Wbf,
                             float* __restrict__ cvec) {
    __shared__ float worow[DD];
    __shared__ float part[DD];
    const int i = blockIdx.x;   // output row of W
    const int j = threadIdx.x;  // output col of W
    worow[j] = out_w[i * DD + j];
    __syncthreads();
    const float* wv = in_w + 512 * DD;  // Wv = rows 512..767 of in_proj_w
    float s = 0.f;
    for (int k = 0; k < DD; ++k) s = fmaf(worow[k], wv[k * DD + j], s);
    Wbf[i * DD + j] = f2bf(s);
    part[j] = worow[j] * in_b[512 + j];  // bv[j]
    __syncthreads();
    if (j == 0) {
        float c = out_b[i];
        for (int k = 0; k < DD; ++k) c += part[k];
        cvec[i] = c;
    }
}

// ---------------- main fused kernel ----------------
// 512 blocks x 512 threads, 2 blocks/CU (LDS 70.8 KiB). W in registers
// (each wave owns 32 out-cols). Per iter: 32 rows streamed through LDS.
__global__ __launch_bounds__(512, 4) void fused_kernel(
    const float* __restrict__ x, const unsigned short* __restrict__ Wbf,
    const float* __restrict__ cvec, const float* __restrict__ gamma,
    const float* __restrict__ beta, float* __restrict__ out) {
    extern __shared__ __align__(16) char lds[];
    const int tid = threadIdx.x;
    const int w = tid >> 6, lane = tid & 63;
    const int m = lane & 15, g = lane >> 4;

    // A fragments: af[n2][s] = W[w*32+n2*16+m][k = s*32+g*8 .. +8]  (64 VGPRs)
    short8 af[2][8];
#pragma unroll
    for (int n2 = 0; n2 < 2; ++n2)
#pragma unroll
        for (int s = 0; s < 8; ++s)
            af[n2][s] = *(const short8*)(Wbf + (w * 32 + n2 * 16 + m) * 256 + s * 32 + g * 8);

    // c, gamma, beta -> LDS (keeps VGPRs under 128 for 4 waves/SIMD)
    if (tid < 256) {
        *(float*)(lds + CGB + tid * 4) = cvec[tid];
        *(float*)(lds + CGB + 1024 + tid * 4) = gamma[tid];
        *(float*)(lds + CGB + 2048 + tid * 4) = beta[tid];
    }

    const size_t rowbase = (size_t)blockIdx.x * (ITERS * RPI);

    f32x4 sv[4];
    // prologue: stage iter 0 into buffer 0
#pragma unroll
    for (int j = 0; j < 4; ++j)
        sv[j] = *(const f32x4*)(x + rowbase * DD + j * 2048 + tid * 4);
#pragma unroll
    for (int j = 0; j < 4; ++j) {
        const int row = j * 8 + w;
        u16x4 h = {f2bf(sv[j][0]), f2bf(sv[j][1]), f2bf(sv[j][2]), f2bf(sv[j][3])};
        *(u16x4*)(lds + XB0 + row * XROW + lane * 8) = h;
    }
    __syncthreads();

    for (int it = 0; it < ITERS; ++it) {
        const int xb = (it & 1) ? XB1 : XB0;
        const int xn = (it & 1) ? XB0 : XB1;
        const size_t r0 = rowbase + (size_t)it * RPI;

        // T14: issue next tile's global loads now, consume after compute
        if (it + 1 < ITERS) {
#pragma unroll
            for (int j = 0; j < 4; ++j)
                sv[j] = *(const f32x4*)(x + (r0 + RPI) * DD + j * 2048 + tid * 4);
        }

        // MFMA phase: B = partner rows from LDS
        f32x4 acc[2][2];
#pragma unroll
        for (int t = 0; t < 2; ++t) {
            acc[t][0] = f32x4{0.f, 0.f, 0.f, 0.f};
            acc[t][1] = f32x4{0.f, 0.f, 0.f, 0.f};
        }
#pragma unroll
        for (int t = 0; t < 2; ++t) {
            const int rowp = t * 16 + (m ^ 1);  // partner row
            const char* bbase = lds + xb + rowp * XROW + g * 16;
            short8 bf_[8];
#pragma unroll
            for (int s = 0; s < 8; ++s) bf_[s] = *(const short8*)(bbase + s * 64);
#pragma unroll
            for (int s = 0; s < 8; ++s) {
                acc[t][0] = __builtin_amdgcn_mfma_f32_16x16x32_bf16(af[0][s], bf_[s], acc[t][0], 0, 0, 0);
                acc[t][1] = __builtin_amdgcn_mfma_f32_16x16x32_bf16(af[1][s], bf_[s], acc[t][1], 0, 0, 0);
            }
        }

        // residual (bf16 from LDS) + bias, partial LN sums -> LDS
#pragma unroll
        for (int t = 0; t < 2; ++t) {
            const int rowm = t * 16 + m;
            float s1 = 0.f, s2 = 0.f;
#pragma unroll
            for (int n2 = 0; n2 < 2; ++n2) {
                u16x4 rh = *(const u16x4*)(lds + xb + rowm * XROW + w * 64 + n2 * 32 + g * 8);
                f32x4 cc = *(const f32x4*)(lds + CGB + (w * 32 + n2 * 16 + g * 4) * 4);
                f32x4 y = acc[t][n2];
#pragma unroll
                for (int i = 0; i < 4; ++i) y[i] += bf2f(rh[i]) + cc[i];
                acc[t][n2] = y;
#pragma unroll
                for (int i = 0; i < 4; ++i) {
                    s1 += y[i];
                    s2 = fmaf(y[i], y[i], s2);
                }
            }
            s1 += __shfl_xor(s1, 16); s2 += __shfl_xor(s2, 16);
            s1 += __shfl_xor(s1, 32); s2 += __shfl_xor(s2, 32);
            if (g == 0) *(f32x2*)(lds + SUMS + (rowm * 8 + w) * 8) = f32x2{s1, s2};
        }
        __syncthreads();

        // cross-wave LN reduce: 32 rows x 8 partials = 256 threads
        if (tid < 256) {
            const int r = tid >> 3, w2 = tid & 7;
            f32x2 p = *(const f32x2*)(lds + SUMS + (r * 8 + w2) * 8);
            float a = p[0], b = p[1];
            a += __shfl_xor(a, 1); b += __shfl_xor(b, 1);
            a += __shfl_xor(a, 2); b += __shfl_xor(b, 2);
            a += __shfl_xor(a, 4); b += __shfl_xor(b, 4);
            if (w2 == 0) {
                const float mu = a * (1.f / 256.f);
                const float var = b * (1.f / 256.f) - mu * mu;
                *(f32x2*)(lds + MURS + r * 8) = f32x2{mu, rsqrtf(var + 1e-5f)};
            }
        }
        __syncthreads();

        // normalize -> ybuf (LDS fp32)
#pragma unroll
        for (int t = 0; t < 2; ++t) {
            const int rowm = t * 16 + m;
            f32x2 mr = *(const f32x2*)(lds + MURS + rowm * 8);
#pragma unroll
            for (int n2 = 0; n2 < 2; ++n2) {
                f32x4 gg = *(const f32x4*)(lds + CGB + 1024 + (w * 32 + n2 * 16 + g * 4) * 4);
                f32x4 bb = *(const f32x4*)(lds + CGB + 2048 + (w * 32 + n2 * 16 + g * 4) * 4);
                f32x4 y = acc[t][n2], o;
#pragma unroll
                for (int i = 0; i < 4; ++i)
                    o[i] = fmaf((y[i] - mr[0]) * mr[1], gg[i], bb[i]);
                *(f32x4*)(lds + YB + rowm * YROW + w * 128 + n2 * 64 + g * 16) = o;
            }
        }

        // consume prefetch: cvt + write bf16 tile for next iter
        if (it + 1 < ITERS) {
#pragma unroll
            for (int j = 0; j < 4; ++j) {
                const int row = j * 8 + w;
                u16x4 h = {f2bf(sv[j][0]), f2bf(sv[j][1]), f2bf(sv[j][2]), f2bf(sv[j][3])};
                *(u16x4*)(lds + xn + row * XROW + lane * 8) = h;
            }
        }
        __syncthreads();

        // coalesced store: each wave writes full contiguous rows
#pragma unroll
        for (int j = 0; j < 4; ++j) {
            const int row = j * 8 + w;
            f32x4 v = *(const f32x4*)(lds + YB + row * YROW + lane * 16);
            *(f32x4*)(out + (r0 + row) * DD + lane * 4) = v;
        }
    }
}

extern "C" void kernel_launch(void* const* d_in, const int* in_sizes, int n_in,
                              void* d_out, int out_size, void* d_ws, size_t ws_size,
                              hipStream_t stream) {
    const float* x     = (const float*)d_in[0];
    const float* in_w  = (const float*)d_in[1];
    const float* in_b  = (const float*)d_in[2];
    const float* out_w = (const float*)d_in[3];
    const float* out_b = (const float*)d_in[4];
    const float* gamma = (const float*)d_in[5];
    const float* beta  = (const float*)d_in[6];
    float* out = (float*)d_out;

    unsigned short* Wbf = (unsigned short*)d_ws;   // 128 KiB bf16 W = Wo@Wv
    float* cvec = (float*)((char*)d_ws + 131072);  // 1 KiB c = Wo@bv + bo

    hipLaunchKernelGGL(wprep_kernel, dim3(256), dim3(256), 0, stream,
                       in_w, in_b, out_w, out_b, Wbf, cvec);

    hipFuncSetAttribute(reinterpret_cast<const void*>(fused_kernel),
                        hipFuncAttributeMaxDynamicSharedMemorySize, LDS_TOTAL);
    hipLaunchKernelGGL(fused_kernel, dim3(NBLOCKS), dim3(512), LDS_TOTAL, stream,
                       x, Wbf, cvec, gamma, beta, out);
}

// Round 4
// 439.232 us; speedup vs baseline: 1.2895x; 1.2895x over previous
//
#include <hip/hip_runtime.h>

#define DD 256
#define TOTROWS (524288 * 2)
#define NBLOCKS 256
#define RPI 64                               // rows per iteration per block
#define ITERS (TOTROWS / (NBLOCKS * RPI))    // 64
#define XROW 528                             // bf16 row stride bytes (16B pad -> conflict-floor)
#define XBUF(i) ((i) * (RPI * XROW))         // x tiles (bf16), double buffered
#define YBUF(i) (2 * RPI * XROW + (i) * (RPI * XROW))  // y tiles (bf16), double buffered
#define LDS_TOTAL (4 * RPI * XROW)           // 135168 -> 1 block/CU

typedef __attribute__((ext_vector_type(8))) short short8;
typedef __attribute__((ext_vector_type(4))) float f32x4;
typedef __attribute__((ext_vector_type(4))) unsigned short u16x4;

__device__ inline unsigned short f2bf(float x) {
    unsigned u = __builtin_bit_cast(unsigned, x);
    u += 0x7fffu + ((u >> 16) & 1u);  // RNE
    return (unsigned short)(u >> 16);
}
__device__ inline float bf2f(unsigned short h) {
    unsigned u = ((unsigned)h) << 16;
    return __builtin_bit_cast(float, u);
}

// ---------------- W = Wo @ Wv (bf16), c = Wo @ bv + bo ----------------
__global__ void wprep_kernel(const float* __restrict__ in_w,
                             const float* __restrict__ in_b,
                             const float* __restrict__ out_w,
                             const float* __restrict__ out_b,
                             unsigned short* __restrict__ Wbf,
                             float* __restrict__ cvec) {
    __shared__ float worow[DD];
    __shared__ float part[DD];
    const int i = blockIdx.x;
    const int j = threadIdx.x;
    worow[j] = out_w[i * DD + j];
    __syncthreads();
    const float* wv = in_w + 512 * DD;  // Wv = rows 512..767 of in_proj_w
    float s = 0.f;
    for (int k = 0; k < DD; ++k) s = fmaf(worow[k], wv[k * DD + j], s);
    Wbf[i * DD + j] = f2bf(s);
    part[j] = worow[j] * in_b[512 + j];  // bv[j]
    __syncthreads();
    if (j == 0) {
        float c = out_b[i];
        for (int k = 0; k < DD; ++k) c += part[k];
        cvec[i] = c;
    }
}

// ---------------- main fused kernel ----------------
// 256 blocks x 512 threads, 1 block/CU. W in regs (32 out-cols/wave).
// ONE barrier/iter: [prefetch issue | LN+store of iter-1 from ybuf | MFMA+
// residual -> ybuf (bf16) | cvt+write next x tile] -> barrier.
__global__ __launch_bounds__(512, 2) void fused_kernel(
    const float* __restrict__ x, const unsigned short* __restrict__ Wbf,
    const float* __restrict__ cvec, const float* __restrict__ gamma,
    const float* __restrict__ beta, float* __restrict__ out) {
    extern __shared__ __align__(16) char lds[];
    const int tid = threadIdx.x;
    const int w = tid >> 6, lane = tid & 63;
    const int m = lane & 15, g = lane >> 4;
    const int lc = lane & 7, lr = lane >> 3;  // LN-phase: row-group / col-chunk

    // A fragments: af[n2][s] = W[w*32+n2*16+m][s*32+g*8 ..]  (64 VGPRs)
    short8 af[2][8];
#pragma unroll
    for (int n2 = 0; n2 < 2; ++n2)
#pragma unroll
        for (int s = 0; s < 8; ++s)
            af[n2][s] = *(const short8*)(Wbf + (w * 32 + n2 * 16 + m) * 256 + s * 32 + g * 8);

    // bias for this wave's cols; gamma/beta for this lane's LN col pattern
    f32x4 creg[2];
#pragma unroll
    for (int n2 = 0; n2 < 2; ++n2)
        creg[n2] = *(const f32x4*)(cvec + w * 32 + n2 * 16 + g * 4);
    f32x4 gg[8], bb[8];
#pragma unroll
    for (int k = 0; k < 8; ++k) {
        gg[k] = *(const f32x4*)(gamma + lc * 4 + k * 32);
        bb[k] = *(const f32x4*)(beta + lc * 4 + k * 32);
    }

    const size_t rowbase = (size_t)blockIdx.x * (ITERS * RPI);

    f32x4 sv[8];
    // prologue: stage iter 0 into xbuf[0]
#pragma unroll
    for (int j = 0; j < 8; ++j)
        sv[j] = *(const f32x4*)(x + rowbase * DD + j * 2048 + tid * 4);
#pragma unroll
    for (int j = 0; j < 8; ++j) {
        const int row = j * 8 + w;
        u16x4 h = {f2bf(sv[j][0]), f2bf(sv[j][1]), f2bf(sv[j][2]), f2bf(sv[j][3])};
        *(u16x4*)(lds + XBUF(0) + row * XROW + lane * 8) = h;
    }
    __syncthreads();

    for (int it = 0; it < ITERS; ++it) {
        const int xbc = XBUF(it & 1);
        const int xbn = XBUF((it + 1) & 1);
        const int ybA = YBUF(it & 1);
        const int ybB = YBUF((it + 1) & 1);  // == (it-1)&1
        const size_t r0 = rowbase + (size_t)it * RPI;

        // (1) issue next tile's global loads (consumed at (5))
        if (it + 1 < ITERS) {
#pragma unroll
            for (int j = 0; j < 8; ++j)
                sv[j] = *(const f32x4*)(x + (r0 + RPI) * DD + j * 2048 + tid * 4);
        }

        // (2) LN + store of previous iteration (reads ybB, written last iter)
        if (it > 0) {
            const size_t rp = r0 - RPI + w * 8 + lr;  // this lane's global row
            u16x4 yh[8];
#pragma unroll
            for (int k = 0; k < 8; ++k)
                yh[k] = *(const u16x4*)(lds + ybB + (w * 8 + lr) * XROW + lc * 8 + k * 64);
            float s1 = 0.f, s2 = 0.f;
            float f[8][4];
#pragma unroll
            for (int k = 0; k < 8; ++k)
#pragma unroll
                for (int e = 0; e < 4; ++e) {
                    float v = bf2f(yh[k][e]);
                    f[k][e] = v;
                    s1 += v;
                    s2 = fmaf(v, v, s2);
                }
            s1 += __shfl_xor(s1, 1); s2 += __shfl_xor(s2, 1);
            s1 += __shfl_xor(s1, 2); s2 += __shfl_xor(s2, 2);
            s1 += __shfl_xor(s1, 4); s2 += __shfl_xor(s2, 4);
            const float mu = s1 * (1.f / 256.f);
            const float var = s2 * (1.f / 256.f) - mu * mu;
            const float rs = rsqrtf(var + 1e-5f);
#pragma unroll
            for (int k = 0; k < 8; ++k) {
                f32x4 o;
#pragma unroll
                for (int e = 0; e < 4; ++e)
                    o[e] = fmaf((f[k][e] - mu) * rs, gg[k][e], bb[k][e]);
                *(f32x4*)(out + rp * DD + lc * 4 + k * 32) = o;  // 128B/row per instr
            }
        }

        // (3) MFMA from xbc; residual + bias; y -> ybA (bf16)
        f32x4 acc[4][2];
#pragma unroll
        for (int t = 0; t < 4; ++t) {
            acc[t][0] = f32x4{0.f, 0.f, 0.f, 0.f};
            acc[t][1] = f32x4{0.f, 0.f, 0.f, 0.f};
        }
#pragma unroll
        for (int t = 0; t < 4; ++t) {
            const int rowp = t * 16 + (m ^ 1);  // partner row
            const char* bbase = lds + xbc + rowp * XROW + g * 16;
#pragma unroll
            for (int s = 0; s < 8; ++s) {
                short8 bf_ = *(const short8*)(bbase + s * 64);
                acc[t][0] = __builtin_amdgcn_mfma_f32_16x16x32_bf16(af[0][s], bf_, acc[t][0], 0, 0, 0);
                acc[t][1] = __builtin_amdgcn_mfma_f32_16x16x32_bf16(af[1][s], bf_, acc[t][1], 0, 0, 0);
            }
        }
#pragma unroll
        for (int t = 0; t < 4; ++t) {
            const int rowm = t * 16 + m;
#pragma unroll
            for (int n2 = 0; n2 < 2; ++n2) {
                u16x4 rh = *(const u16x4*)(lds + xbc + rowm * XROW + w * 64 + n2 * 32 + g * 8);
                f32x4 y = acc[t][n2];
#pragma unroll
                for (int i = 0; i < 4; ++i) y[i] += bf2f(rh[i]) + creg[n2][i];
                u16x4 hy = {f2bf(y[0]), f2bf(y[1]), f2bf(y[2]), f2bf(y[3])};
                *(u16x4*)(lds + ybA + rowm * XROW + w * 64 + n2 * 32 + g * 8) = hy;
            }
        }

        // (5) consume prefetch: cvt + write next x tile
        if (it + 1 < ITERS) {
#pragma unroll
            for (int j = 0; j < 8; ++j) {
                const int row = j * 8 + w;
                u16x4 h = {f2bf(sv[j][0]), f2bf(sv[j][1]), f2bf(sv[j][2]), f2bf(sv[j][3])};
                *(u16x4*)(lds + xbn + row * XROW + lane * 8) = h;
            }
        }
        __syncthreads();
    }

    // epilogue: LN + store for last iteration (ybuf[(ITERS-1)&1])
    {
        const int ybB = YBUF((ITERS - 1) & 1);
        const size_t rp = rowbase + (size_t)(ITERS - 1) * RPI + w * 8 + lr;
        u16x4 yh[8];
#pragma unroll
        for (int k = 0; k < 8; ++k)
            yh[k] = *(const u16x4*)(lds + ybB + (w * 8 + lr) * XROW + lc * 8 + k * 64);
        float s1 = 0.f, s2 = 0.f;
        float f[8][4];
#pragma unroll
        for (int k = 0; k < 8; ++k)
#pragma unroll
            for (int e = 0; e < 4; ++e) {
                float v = bf2f(yh[k][e]);
                f[k][e] = v;
                s1 += v;
                s2 = fmaf(v, v, s2);
            }
        s1 += __shfl_xor(s1, 1); s2 += __shfl_xor(s2, 1);
        s1 += __shfl_xor(s1, 2); s2 += __shfl_xor(s2, 2);
        s1 += __shfl_xor(s1, 4); s2 += __shfl_xor(s2, 4);
        const float mu = s1 * (1.f / 256.f);
        const float var = s2 * (1.f / 256.f) - mu * mu;
        const float rs = rsqrtf(var + 1e-5f);
#pragma unroll
        for (int k = 0; k < 8; ++k) {
            f32x4 o;
#pragma unroll
            for (int e = 0; e < 4; ++e)
                o[e] = fmaf((f[k][e] - mu) * rs, gg[k][e], bb[k][e]);
            *(f32x4*)(out + rp * DD + lc * 4 + k * 32) = o;
        }
    }
}

extern "C" void kernel_launch(void* const* d_in, const int* in_sizes, int n_in,
                              void* d_out, int out_size, void* d_ws, size_t ws_size,
                              hipStream_t stream) {
    const float* x     = (const float*)d_in[0];
    const float* in_w  = (const float*)d_in[1];
    const float* in_b  = (const float*)d_in[2];
    const float* out_w = (const float*)d_in[3];
    const float* out_b = (const float*)d_in[4];
    const float* gamma = (const float*)d_in[5];
    const float* beta  = (const float*)d_in[6];
    float* out = (float*)d_out;

    unsigned short* Wbf = (unsigned short*)d_ws;   // 128 KiB bf16 W = Wo@Wv
    float* cvec = (float*)((char*)d_ws + 131072);  // 1 KiB c = Wo@bv + bo

    hipLaunchKernelGGL(wprep_kernel, dim3(256), dim3(256), 0, stream,
                       in_w, in_b, out_w, out_b, Wbf, cvec);

    hipFuncSetAttribute(reinterpret_cast<const void*>(fused_kernel),
                        hipFuncAttributeMaxDynamicSharedMemorySize, LDS_TOTAL);
    hipLaunchKernelGGL(fused_kernel, dim3(NBLOCKS), dim3(512), LDS_TOTAL, stream,
                       x, Wbf, cvec, gamma, beta, out);
}

// Round 5
// 420.052 us; speedup vs baseline: 1.3484x; 1.0457x over previous
//
#include <hip/hip_runtime.h>

#define DD 256
#define TOTROWS (524288 * 2)
#define NBLOCKS 256
#define RPI 64                               // rows per iteration per block
#define ITERS (TOTROWS / (NBLOCKS * RPI))    // 64
#define XROW 528                             // bf16 row stride bytes (16B pad -> conflict-floor)
#define XBUF(i) ((i) * (RPI * XROW))         // x tiles (bf16), double buffered
#define YBUF(i) (2 * RPI * XROW + (i) * (RPI * XROW))  // y tiles (bf16), double buffered
#define LDS_TOTAL (4 * RPI * XROW)           // 135168 -> 1 block/CU

typedef __attribute__((ext_vector_type(8))) short short8;
typedef __attribute__((ext_vector_type(4))) float f32x4;
typedef __attribute__((ext_vector_type(4))) unsigned short u16x4;

__device__ inline unsigned short f2bf(float x) {
    unsigned u = __builtin_bit_cast(unsigned, x);
    u += 0x7fffu + ((u >> 16) & 1u);  // RNE
    return (unsigned short)(u >> 16);
}
__device__ inline float bf2f(unsigned short h) {
    unsigned u = ((unsigned)h) << 16;
    return __builtin_bit_cast(float, u);
}

// LDS-only barrier: orders ds ops across waves WITHOUT draining global
// stores / in-flight prefetch loads (vmcnt untouched). All cross-wave
// hazards in the loop are LDS (xbuf/ybuf); sv loads are within-wave
// (compiler-counted vmcnt) and out-stores are never read back.
__device__ inline void block_sync_lds() {
    __builtin_amdgcn_sched_barrier(0);
    asm volatile("s_waitcnt lgkmcnt(0)" ::: "memory");
    __builtin_amdgcn_s_barrier();
    __builtin_amdgcn_sched_barrier(0);
}

// ---------------- W = Wo @ Wv (bf16), c = Wo @ bv + bo ----------------
__global__ void wprep_kernel(const float* __restrict__ in_w,
                             const float* __restrict__ in_b,
                             const float* __restrict__ out_w,
                             const float* __restrict__ out_b,
                             unsigned short* __restrict__ Wbf,
                             float* __restrict__ cvec) {
    __shared__ float worow[DD];
    __shared__ float part[DD];
    const int i = blockIdx.x;
    const int j = threadIdx.x;
    worow[j] = out_w[i * DD + j];
    __syncthreads();
    const float* wv = in_w + 512 * DD;  // Wv = rows 512..767 of in_proj_w
    float s = 0.f;
    for (int k = 0; k < DD; ++k) s = fmaf(worow[k], wv[k * DD + j], s);
    Wbf[i * DD + j] = f2bf(s);
    part[j] = worow[j] * in_b[512 + j];  // bv[j]
    __syncthreads();
    if (j == 0) {
        float c = out_b[i];
        for (int k = 0; k < DD; ++k) c += part[k];
        cvec[i] = c;
    }
}

// ---------------- main fused kernel ----------------
// 256 blocks x 512 threads, 1 block/CU. W in regs (32 out-cols/wave).
// Per region: [LN+nt-store of it-1 | MFMA(it)+residual -> ybuf | stage
// x(it+1) from sv | issue sv loads for it+2] -> LDS-only barrier.
// Loads are in flight ~1.3 iterations; stores never drained at barriers.
__global__ __launch_bounds__(512, 2) void fused_kernel(
    const float* __restrict__ x, const unsigned short* __restrict__ Wbf,
    const float* __restrict__ cvec, const float* __restrict__ gamma,
    const float* __restrict__ beta, float* __restrict__ out) {
    extern __shared__ __align__(16) char lds[];
    const int tid = threadIdx.x;
    const int w = tid >> 6, lane = tid & 63;
    const int m = lane & 15, g = lane >> 4;
    const int lc = lane & 7, lr = lane >> 3;  // LN-phase: col-chunk / row

    // A fragments: af[n2][s] = W[w*32+n2*16+m][s*32+g*8 ..]  (64 VGPRs)
    short8 af[2][8];
#pragma unroll
    for (int n2 = 0; n2 < 2; ++n2)
#pragma unroll
        for (int s = 0; s < 8; ++s)
            af[n2][s] = *(const short8*)(Wbf + (w * 32 + n2 * 16 + m) * 256 + s * 32 + g * 8);

    f32x4 creg[2];
#pragma unroll
    for (int n2 = 0; n2 < 2; ++n2)
        creg[n2] = *(const f32x4*)(cvec + w * 32 + n2 * 16 + g * 4);
    f32x4 gg[8], bb[8];
#pragma unroll
    for (int k = 0; k < 8; ++k) {
        gg[k] = *(const f32x4*)(gamma + lc * 4 + k * 32);
        bb[k] = *(const f32x4*)(beta + lc * 4 + k * 32);
    }

    const size_t rowbase = (size_t)blockIdx.x * (ITERS * RPI);

    f32x4 sv[8];
    // prologue: load + stage x(iter0) into xbuf[0]
#pragma unroll
    for (int j = 0; j < 8; ++j)
        sv[j] = *(const f32x4*)(x + rowbase * DD + j * 2048 + tid * 4);
#pragma unroll
    for (int j = 0; j < 8; ++j) {
        const int row = j * 8 + w;
        u16x4 h = {f2bf(sv[j][0]), f2bf(sv[j][1]), f2bf(sv[j][2]), f2bf(sv[j][3])};
        *(u16x4*)(lds + XBUF(0) + row * XROW + lane * 8) = h;
    }
    // issue loads for iter1 (consumed next region)
#pragma unroll
    for (int j = 0; j < 8; ++j)
        sv[j] = *(const f32x4*)(x + (rowbase + RPI) * DD + j * 2048 + tid * 4);
    block_sync_lds();

    for (int it = 0; it < ITERS; ++it) {
        const int xbc = XBUF(it & 1);
        const int xbn = XBUF((it + 1) & 1);
        const int ybA = YBUF(it & 1);
        const int ybB = YBUF((it + 1) & 1);  // == (it-1)&1
        const size_t r0 = rowbase + (size_t)it * RPI;

        // (1) LN + nt-store of previous iteration (reads ybB, written last region)
        if (it > 0) {
            const size_t rp = r0 - RPI + w * 8 + lr;  // this lane's global row
            u16x4 yh[8];
#pragma unroll
            for (int k = 0; k < 8; ++k)
                yh[k] = *(const u16x4*)(lds + ybB + (w * 8 + lr) * XROW + lc * 8 + k * 64);
            float s1 = 0.f, s2 = 0.f;
            float f[8][4];
#pragma unroll
            for (int k = 0; k < 8; ++k)
#pragma unroll
                for (int e = 0; e < 4; ++e) {
                    float v = bf2f(yh[k][e]);
                    f[k][e] = v;
                    s1 += v;
                    s2 = fmaf(v, v, s2);
                }
            s1 += __shfl_xor(s1, 1); s2 += __shfl_xor(s2, 1);
            s1 += __shfl_xor(s1, 2); s2 += __shfl_xor(s2, 2);
            s1 += __shfl_xor(s1, 4); s2 += __shfl_xor(s2, 4);
            const float mu = s1 * (1.f / 256.f);
            const float var = s2 * (1.f / 256.f) - mu * mu;
            const float rs = rsqrtf(var + 1e-5f);
#pragma unroll
            for (int k = 0; k < 8; ++k) {
                f32x4 o;
#pragma unroll
                for (int e = 0; e < 4; ++e)
                    o[e] = fmaf((f[k][e] - mu) * rs, gg[k][e], bb[k][e]);
                __builtin_nontemporal_store(o, (f32x4*)(out + rp * DD + lc * 4 + k * 32));
            }
        }

        // (2) MFMA from xbc; residual + bias; y -> ybA (bf16)
        f32x4 acc[4][2];
#pragma unroll
        for (int t = 0; t < 4; ++t) {
            acc[t][0] = f32x4{0.f, 0.f, 0.f, 0.f};
            acc[t][1] = f32x4{0.f, 0.f, 0.f, 0.f};
        }
#pragma unroll
        for (int t = 0; t < 4; ++t) {
            const int rowp = t * 16 + (m ^ 1);  // partner row
            const char* bbase = lds + xbc + rowp * XROW + g * 16;
#pragma unroll
            for (int s = 0; s < 8; ++s) {
                short8 bf_ = *(const short8*)(bbase + s * 64);
                acc[t][0] = __builtin_amdgcn_mfma_f32_16x16x32_bf16(af[0][s], bf_, acc[t][0], 0, 0, 0);
                acc[t][1] = __builtin_amdgcn_mfma_f32_16x16x32_bf16(af[1][s], bf_, acc[t][1], 0, 0, 0);
            }
        }
#pragma unroll
        for (int t = 0; t < 4; ++t) {
            const int rowm = t * 16 + m;
#pragma unroll
            for (int n2 = 0; n2 < 2; ++n2) {
                u16x4 rh = *(const u16x4*)(lds + xbc + rowm * XROW + w * 64 + n2 * 32 + g * 8);
                f32x4 y = acc[t][n2];
#pragma unroll
                for (int i = 0; i < 4; ++i) y[i] += bf2f(rh[i]) + creg[n2][i];
                u16x4 hy = {f2bf(y[0]), f2bf(y[1]), f2bf(y[2]), f2bf(y[3])};
                *(u16x4*)(lds + ybA + rowm * XROW + w * 64 + n2 * 32 + g * 8) = hy;
            }
        }

        // (3) consume prefetch (x of it+1): cvt + write next x tile
        if (it + 1 < ITERS) {
#pragma unroll
            for (int j = 0; j < 8; ++j) {
                const int row = j * 8 + w;
                u16x4 h = {f2bf(sv[j][0]), f2bf(sv[j][1]), f2bf(sv[j][2]), f2bf(sv[j][3])};
                *(u16x4*)(lds + xbn + row * XROW + lane * 8) = h;
            }
        }
        // (4) issue loads for it+2 BEFORE the barrier (in flight ~1.3 iters)
        if (it + 2 < ITERS) {
#pragma unroll
            for (int j = 0; j < 8; ++j)
                sv[j] = *(const f32x4*)(x + (r0 + 2 * RPI) * DD + j * 2048 + tid * 4);
        }
        block_sync_lds();
    }

    // epilogue: LN + store for last iteration (ybuf[(ITERS-1)&1])
    {
        const int ybB = YBUF((ITERS - 1) & 1);
        const size_t rp = rowbase + (size_t)(ITERS - 1) * RPI + w * 8 + lr;
        u16x4 yh[8];
#pragma unroll
        for (int k = 0; k < 8; ++k)
            yh[k] = *(const u16x4*)(lds + ybB + (w * 8 + lr) * XROW + lc * 8 + k * 64);
        float s1 = 0.f, s2 = 0.f;
        float f[8][4];
#pragma unroll
        for (int k = 0; k < 8; ++k)
#pragma unroll
            for (int e = 0; e < 4; ++e) {
                float v = bf2f(yh[k][e]);
                f[k][e] = v;
                s1 += v;
                s2 = fmaf(v, v, s2);
            }
        s1 += __shfl_xor(s1, 1); s2 += __shfl_xor(s2, 1);
        s1 += __shfl_xor(s1, 2); s2 += __shfl_xor(s2, 2);
        s1 += __shfl_xor(s1, 4); s2 += __shfl_xor(s2, 4);
        const float mu = s1 * (1.f / 256.f);
        const float var = s2 * (1.f / 256.f) - mu * mu;
        const float rs = rsqrtf(var + 1e-5f);
#pragma unroll
        for (int k = 0; k < 8; ++k) {
            f32x4 o;
#pragma unroll
            for (int e = 0; e < 4; ++e)
                o[e] = fmaf((f[k][e] - mu) * rs, gg[k][e], bb[k][e]);
            __builtin_nontemporal_store(o, (f32x4*)(out + rp * DD + lc * 4 + k * 32));
        }
    }
}

extern "C" void kernel_launch(void* const* d_in, const int* in_sizes, int n_in,
                              void* d_out, int out_size, void* d_ws, size_t ws_size,
                              hipStream_t stream) {
    const float* x     = (const float*)d_in[0];
    const float* in_w  = (const float*)d_in[1];
    const float* in_b  = (const float*)d_in[2];
    const float* out_w = (const float*)d_in[3];
    const float* out_b = (const float*)d_in[4];
    const float* gamma = (const float*)d_in[5];
    const float* beta  = (const float*)d_in[6];
    float* out = (float*)d_out;

    unsigned short* Wbf = (unsigned short*)d_ws;   // 128 KiB bf16 W = Wo@Wv
    float* cvec = (float*)((char*)d_ws + 131072);  // 1 KiB c = Wo@bv + bo

    hipLaunchKernelGGL(wprep_kernel, dim3(256), dim3(256), 0, stream,
                       in_w, in_b, out_w, out_b, Wbf, cvec);

    hipFuncSetAttribute(reinterpret_cast<const void*>(fused_kernel),
                        hipFuncAttributeMaxDynamicSharedMemorySize, LDS_TOTAL);
    hipLaunchKernelGGL(fused_kernel, dim3(NBLOCKS), dim3(512), LDS_TOTAL, stream,
                       x, Wbf, cvec, gamma, beta, out);
}

// Round 6
// 419.229 us; speedup vs baseline: 1.3510x; 1.0020x over previous
//
#include <hip/hip_runtime.h>

#define DD 256
#define TOTROWS (524288 * 2)
#define NBLOCKS 256
#define RPI 32                               // rows per region per block
#define ITERS (TOTROWS / (NBLOCKS * RPI))    // 128
#define XROW 528                             // bf16 row stride bytes (16B pad)
#define XBUF(i) ((i) * (RPI * XROW))         // 4 x tiles (bf16)
#define YBUF(i) (4 * RPI * XROW + (i) * (RPI * XROW))  // 2 y tiles (bf16)
#define LDS_TOTAL (6 * RPI * XROW)           // 101376 -> 1 block/CU

typedef __attribute__((ext_vector_type(8))) short short8;
typedef __attribute__((ext_vector_type(4))) float f32x4;
typedef __attribute__((ext_vector_type(4))) unsigned short u16x4;

__device__ inline unsigned short f2bf(float x) {
    unsigned u = __builtin_bit_cast(unsigned, x);
    u += 0x7fffu + ((u >> 16) & 1u);  // RNE
    return (unsigned short)(u >> 16);
}
__device__ inline float bf2f(unsigned short h) {
    unsigned u = ((unsigned)h) << 16;
    return __builtin_bit_cast(float, u);
}

// LDS-only barrier: orders ds ops across waves WITHOUT draining in-flight
// global loads/stores (vmcnt untouched). All cross-wave hazards are LDS.
__device__ inline void block_sync_lds() {
    __builtin_amdgcn_sched_barrier(0);
    asm volatile("s_waitcnt lgkmcnt(0)" ::: "memory");
    __builtin_amdgcn_s_barrier();
    __builtin_amdgcn_sched_barrier(0);
}

// ---------------- W = Wo @ Wv (bf16), c = Wo @ bv + bo ----------------
__global__ void wprep_kernel(const float* __restrict__ in_w,
                             const float* __restrict__ in_b,
                             const float* __restrict__ out_w,
                             const float* __restrict__ out_b,
                             unsigned short* __restrict__ Wbf,
                             float* __restrict__ cvec) {
    __shared__ float worow[DD];
    __shared__ float part[DD];
    const int i = blockIdx.x;
    const int j = threadIdx.x;
    worow[j] = out_w[i * DD + j];
    __syncthreads();
    const float* wv = in_w + 512 * DD;  // Wv = rows 512..767 of in_proj_w
    float s = 0.f;
    for (int k = 0; k < DD; ++k) s = fmaf(worow[k], wv[k * DD + j], s);
    Wbf[i * DD + j] = f2bf(s);
    part[j] = worow[j] * in_b[512 + j];  // bv[j]
    __syncthreads();
    if (j == 0) {
        float c = out_b[i];
        for (int k = 0; k < DD; ++k) c += part[k];
        cvec[i] = c;
    }
}

// ---------------- main fused kernel ----------------
// 256 blocks x 512 threads, 1 block/CU. W in regs (32 out-cols/wave).
// RPI=32 regions, 4 xbuf + 2 sv sets: loads issued 3 regions before
// MFMA-use, 1 region before staging. One LDS-only barrier per region.
__global__ __launch_bounds__(512, 2) void fused_kernel(
    const float* __restrict__ x, const unsigned short* __restrict__ Wbf,
    const float* __restrict__ cvec, const float* __restrict__ gamma,
    const float* __restrict__ beta, float* __restrict__ out) {
    extern __shared__ __align__(16) char lds[];
    const int tid = threadIdx.x;
    const int w = tid >> 6, lane = tid & 63;
    const int m = lane & 15, g = lane >> 4;
    const int lc = lane & 15, lr = tid >> 4;  // LN: 16 lanes/row, rows 0..31

    // A fragments: af[n2][s] = W[w*32+n2*16+m][s*32+g*8 ..]  (64 VGPRs)
    short8 af[2][8];
#pragma unroll
    for (int n2 = 0; n2 < 2; ++n2)
#pragma unroll
        for (int s = 0; s < 8; ++s)
            af[n2][s] = *(const short8*)(Wbf + (w * 32 + n2 * 16 + m) * 256 + s * 32 + g * 8);

    f32x4 creg[2];
#pragma unroll
    for (int n2 = 0; n2 < 2; ++n2)
        creg[n2] = *(const f32x4*)(cvec + w * 32 + n2 * 16 + g * 4);
    f32x4 gg[4], bb[4];
#pragma unroll
    for (int k = 0; k < 4; ++k) {
        gg[k] = *(const f32x4*)(gamma + lc * 4 + k * 64);
        bb[k] = *(const f32x4*)(beta + lc * 4 + k * 64);
    }

    const size_t rowbase = (size_t)blockIdx.x * (ITERS * RPI);

    f32x4 svA[4], svB[4];
    // prologue: stage tiles 0,1; leave tile 2 loaded in svA
#pragma unroll
    for (int j = 0; j < 4; ++j)
        svA[j] = *(const f32x4*)(x + rowbase * DD + j * 2048 + tid * 4);
#pragma unroll
    for (int j = 0; j < 4; ++j) {
        const int row = j * 8 + w;
        u16x4 h = {f2bf(svA[j][0]), f2bf(svA[j][1]), f2bf(svA[j][2]), f2bf(svA[j][3])};
        *(u16x4*)(lds + XBUF(0) + row * XROW + lane * 8) = h;
    }
#pragma unroll
    for (int j = 0; j < 4; ++j)
        svA[j] = *(const f32x4*)(x + (rowbase + RPI) * DD + j * 2048 + tid * 4);
#pragma unroll
    for (int j = 0; j < 4; ++j) {
        const int row = j * 8 + w;
        u16x4 h = {f2bf(svA[j][0]), f2bf(svA[j][1]), f2bf(svA[j][2]), f2bf(svA[j][3])};
        *(u16x4*)(lds + XBUF(1) + row * XROW + lane * 8) = h;
    }
#pragma unroll
    for (int j = 0; j < 4; ++j)
        svA[j] = *(const f32x4*)(x + (rowbase + 2 * RPI) * DD + j * 2048 + tid * 4);
    block_sync_lds();

#define REGION(IT, SVC, SVN)                                                     \
    {                                                                            \
        const int it = (IT);                                                     \
        const int xbc = XBUF(it & 3);                                            \
        const int xbs = XBUF((it + 2) & 3);                                      \
        const int ybA = YBUF(it & 1);                                            \
        const int ybB = YBUF((it + 1) & 1);                                      \
        const size_t r0 = rowbase + (size_t)it * RPI;                            \
        /* (1) LN + nt-store of region it-1 */                                   \
        if (it > 0) {                                                            \
            const size_t rp = r0 - RPI + lr;                                     \
            u16x4 yh[4];                                                         \
            _Pragma("unroll")                                                    \
            for (int k = 0; k < 4; ++k)                                          \
                yh[k] = *(const u16x4*)(lds + ybB + lr * XROW + lc * 8 + k * 128);\
            float s1 = 0.f, s2 = 0.f;                                            \
            float f[4][4];                                                       \
            _Pragma("unroll")                                                    \
            for (int k = 0; k < 4; ++k)                                          \
                _Pragma("unroll")                                                \
                for (int e = 0; e < 4; ++e) {                                    \
                    float v = bf2f(yh[k][e]);                                    \
                    f[k][e] = v;                                                 \
                    s1 += v;                                                     \
                    s2 = fmaf(v, v, s2);                                         \
                }                                                                \
            s1 += __shfl_xor(s1, 1); s2 += __shfl_xor(s2, 1);                    \
            s1 += __shfl_xor(s1, 2); s2 += __shfl_xor(s2, 2);                    \
            s1 += __shfl_xor(s1, 4); s2 += __shfl_xor(s2, 4);                    \
            s1 += __shfl_xor(s1, 8); s2 += __shfl_xor(s2, 8);                    \
            const float mu = s1 * (1.f / 256.f);                                 \
            const float var = s2 * (1.f / 256.f) - mu * mu;                      \
            const float rs = rsqrtf(var + 1e-5f);                                \
            _Pragma("unroll")                                                    \
            for (int k = 0; k < 4; ++k) {                                        \
                f32x4 o;                                                         \
                _Pragma("unroll")                                                \
                for (int e = 0; e < 4; ++e)                                      \
                    o[e] = fmaf((f[k][e] - mu) * rs, gg[k][e], bb[k][e]);        \
                __builtin_nontemporal_store(o, (f32x4*)(out + rp * DD + lc * 4 + k * 64)); \
            }                                                                    \
        }                                                                        \
        /* (2) MFMA from xbc; residual + bias; y -> ybA (bf16) */                \
        f32x4 acc[2][2];                                                         \
        acc[0][0] = f32x4{0.f, 0.f, 0.f, 0.f};                                   \
        acc[0][1] = f32x4{0.f, 0.f, 0.f, 0.f};                                   \
        acc[1][0] = f32x4{0.f, 0.f, 0.f, 0.f};                                   \
        acc[1][1] = f32x4{0.f, 0.f, 0.f, 0.f};                                   \
        _Pragma("unroll")                                                        \
        for (int t = 0; t < 2; ++t) {                                            \
            const int rowp = t * 16 + (m ^ 1);                                   \
            const char* bbase = lds + xbc + rowp * XROW + g * 16;                \
            _Pragma("unroll")                                                    \
            for (int s = 0; s < 8; ++s) {                                        \
                short8 bf_ = *(const short8*)(bbase + s * 64);                   \
                acc[t][0] = __builtin_amdgcn_mfma_f32_16x16x32_bf16(af[0][s], bf_, acc[t][0], 0, 0, 0); \
                acc[t][1] = __builtin_amdgcn_mfma_f32_16x16x32_bf16(af[1][s], bf_, acc[t][1], 0, 0, 0); \
            }                                                                    \
        }                                                                        \
        _Pragma("unroll")                                                        \
        for (int t = 0; t < 2; ++t) {                                            \
            const int rowm = t * 16 + m;                                         \
            _Pragma("unroll")                                                    \
            for (int n2 = 0; n2 < 2; ++n2) {                                     \
                u16x4 rh = *(const u16x4*)(lds + xbc + rowm * XROW + w * 64 + n2 * 32 + g * 8); \
                f32x4 y = acc[t][n2];                                            \
                _Pragma("unroll")                                                \
                for (int i = 0; i < 4; ++i) y[i] += bf2f(rh[i]) + creg[n2][i];   \
                u16x4 hy = {f2bf(y[0]), f2bf(y[1]), f2bf(y[2]), f2bf(y[3])};     \
                *(u16x4*)(lds + ybA + rowm * XROW + w * 64 + n2 * 32 + g * 8) = hy; \
            }                                                                    \
        }                                                                        \
        /* (3) stage SVC (tile it+2) -> xbs */                                   \
        if (it + 2 < ITERS) {                                                    \
            _Pragma("unroll")                                                    \
            for (int j = 0; j < 4; ++j) {                                        \
                const int row = j * 8 + w;                                       \
                u16x4 h = {f2bf(SVC[j][0]), f2bf(SVC[j][1]), f2bf(SVC[j][2]), f2bf(SVC[j][3])}; \
                *(u16x4*)(lds + xbs + row * XROW + lane * 8) = h;                \
            }                                                                    \
        }                                                                        \
        /* (4) issue loads for tile it+3 -> SVN, before the barrier */           \
        if (it + 3 < ITERS) {                                                    \
            _Pragma("unroll")                                                    \
            for (int j = 0; j < 4; ++j)                                          \
                SVN[j] = *(const f32x4*)(x + (r0 + 3 * RPI) * DD + j * 2048 + tid * 4); \
        }                                                                        \
        block_sync_lds();                                                        \
    }

    for (int itb = 0; itb < ITERS; itb += 2) {
        REGION(itb, svA, svB);
        REGION(itb + 1, svB, svA);
    }
#undef REGION

    // epilogue: LN + store for last region (ybuf[(ITERS-1)&1])
    {
        const int ybB = YBUF((ITERS - 1) & 1);
        const size_t rp = rowbase + (size_t)(ITERS - 1) * RPI + lr;
        u16x4 yh[4];
#pragma unroll
        for (int k = 0; k < 4; ++k)
            yh[k] = *(const u16x4*)(lds + ybB + lr * XROW + lc * 8 + k * 128);
        float s1 = 0.f, s2 = 0.f;
        float f[4][4];
#pragma unroll
        for (int k = 0; k < 4; ++k)
#pragma unroll
            for (int e = 0; e < 4; ++e) {
                float v = bf2f(yh[k][e]);
                f[k][e] = v;
                s1 += v;
                s2 = fmaf(v, v, s2);
            }
        s1 += __shfl_xor(s1, 1); s2 += __shfl_xor(s2, 1);
        s1 += __shfl_xor(s1, 2); s2 += __shfl_xor(s2, 2);
        s1 += __shfl_xor(s1, 4); s2 += __shfl_xor(s2, 4);
        s1 += __shfl_xor(s1, 8); s2 += __shfl_xor(s2, 8);
        const float mu = s1 * (1.f / 256.f);
        const float var = s2 * (1.f / 256.f) - mu * mu;
        const float rs = rsqrtf(var + 1e-5f);
#pragma unroll
        for (int k = 0; k < 4; ++k) {
            f32x4 o;
#pragma unroll
            for (int e = 0; e < 4; ++e)
                o[e] = fmaf((f[k][e] - mu) * rs, gg[k][e], bb[k][e]);
            __builtin_nontemporal_store(o, (f32x4*)(out + rp * DD + lc * 4 + k * 64));
        }
    }
}

extern "C" void kernel_launch(void* const* d_in, const int* in_sizes, int n_in,
                              void* d_out, int out_size, void* d_ws, size_t ws_size,
                              hipStream_t stream) {
    const float* x     = (const float*)d_in[0];
    const float* in_w  = (const float*)d_in[1];
    const float* in_b  = (const float*)d_in[2];
    const float* out_w = (const float*)d_in[3];
    const float* out_b = (const float*)d_in[4];
    const float* gamma = (const float*)d_in[5];
    const float* beta  = (const float*)d_in[6];
    float* out = (float*)d_out;

    unsigned short* Wbf = (unsigned short*)d_ws;   // 128 KiB bf16 W = Wo@Wv
    float* cvec = (float*)((char*)d_ws + 131072);  // 1 KiB c = Wo@bv + bo

    hipLaunchKernelGGL(wprep_kernel, dim3(256), dim3(256), 0, stream,
                       in_w, in_b, out_w, out_b, Wbf, cvec);

    hipFuncSetAttribute(reinterpret_cast<const void*>(fused_kernel),
                        hipFuncAttributeMaxDynamicSharedMemorySize, LDS_TOTAL);
    hipLaunchKernelGGL(fused_kernel, dim3(NBLOCKS), dim3(512), LDS_TOTAL, stream,
                       x, Wbf, cvec, gamma, beta, out);
}